// Round 6
// baseline (262.402 us; speedup 1.0000x reference)
//
#include <hip/hip_runtime.h>
#include <math.h>

#define N_NODES 50000
#define N_EDGES 800000
#define IN_DIM_N 128
#define IN_DIM_E 32
#define OUT_DIM 128
#define SCAN_BLOCKS ((N_NODES + 255) / 256)   // 196
#define GEMM_BLOCKS ((N_NODES + 63) / 64)     // 782

typedef __bf16 bf16x8 __attribute__((ext_vector_type(8)));
typedef float  f32x4  __attribute__((ext_vector_type(4)));

// bf16 pack helpers (RNE; data has no NaN/inf)
__device__ inline unsigned bf16_rne(float x) {
    unsigned u = __float_as_uint(x);
    return (u + 0x7FFFu + ((u >> 16) & 1u)) >> 16;
}
__device__ inline unsigned pack_bf2(float a, float b) {
    return bf16_rne(a) | (bf16_rne(b) << 16);
}

// ---- one-off: W_fc (128x128 fp32, W[c][k]) -> bf16 B-fragment layout ----
// Pure 8-block pack (counts zeroing moved to gemm); also re-zeroes the scan
// 'done' flag each launch (graph-replay safe).
__global__ void wfrag_kernel(const float* __restrict__ W, unsigned* __restrict__ Wfrag,
                             int* __restrict__ done) {
    int t = blockIdx.x * 256 + threadIdx.x;   // 0..2047
    if (t == 0) *done = 0;
    if (t >= 2048) return;
    int lane = t & 63;
    int tile = (t >> 6) & 7;
    int ks   = t >> 9;
    int n  = tile * 16 + (lane & 15);
    int kb = ks * 32 + (lane >> 4) * 8;
    const float* srcp = W + n * 128 + kb;     // 8 consecutive k
    unsigned o[4];
#pragma unroll
    for (int j = 0; j < 4; ++j) o[j] = pack_bf2(srcp[2 * j], srcp[2 * j + 1]);
    ((uint4*)Wfrag)[t] = *(uint4*)o;
}

// ---------- MFMA GEMM: 64 rows/block, z bf16 store, fused s_src/s_dst ----------
// B-fragments read DIRECTLY from global Wfrag in the MFMA loop: 32 KB, fits L1,
// identical addresses across waves (broadcast). Also zeroes counts (one
// predicated store/thread; grid 782*256 = 200192 >= N_NODES) — proven free.
__launch_bounds__(256)
__global__ void gemm_mfma_kernel(const float* __restrict__ A, const unsigned* __restrict__ Wfrag,
                                 const float* __restrict__ attn, int* __restrict__ counts,
                                 unsigned* __restrict__ zb,
                                 float* __restrict__ s_src, float* __restrict__ s_dst) {
    __shared__ unsigned Au[64 * 68];    // A bf16, row stride 136 bf16 = 68 u32 (pad kills conflicts)
    __shared__ float asrc[128], adst[128];
    int tid = threadIdx.x;
    int row0 = blockIdx.x * 64;

    int gid = blockIdx.x * 256 + tid;
    if (gid < N_NODES) counts[gid] = 0;

    if (tid < 128) { asrc[tid] = attn[tid]; adst[tid] = attn[160 + tid]; }

    // stage A: 64 rows x 128 k, fp32 -> bf16
    for (int i = tid; i < 64 * 32; i += 256) {
        int r = i >> 5, q = i & 31;
        int gr = row0 + r;
        float4 v = make_float4(0.f, 0.f, 0.f, 0.f);
        if (gr < N_NODES) v = ((const float4*)A)[(long)gr * 32 + q];
        uint2 p = make_uint2(pack_bf2(v.x, v.y), pack_bf2(v.z, v.w));
        *((uint2*)&Au[r * 68 + q * 2]) = p;
    }
    __syncthreads();

    int lane = tid & 63;
    int wave = tid >> 6;
    int m = lane & 15, quad = lane >> 4;
    const uint4* Wg = (const uint4*)Wfrag;

    f32x4 acc[8];
#pragma unroll
    for (int t = 0; t < 8; ++t) acc[t] = (f32x4){0.f, 0.f, 0.f, 0.f};

#pragma unroll
    for (int ks = 0; ks < 4; ++ks) {
        uint4 au = *((const uint4*)&Au[(wave * 16 + m) * 68 + ks * 16 + quad * 4]);
        bf16x8 af = *(bf16x8*)&au;
#pragma unroll
        for (int t = 0; t < 8; ++t) {
            uint4 bu = Wg[(ks * 8 + t) * 64 + lane];   // L1-resident broadcast
            bf16x8 bf = *(bf16x8*)&bu;
            acc[t] = __builtin_amdgcn_mfma_f32_16x16x32_bf16(af, bf, acc[t], 0, 0, 0);
        }
    }

    // epilogue: C/D layout col=lane&15 (+tile*16), row=quad*4+reg
    float ps[4] = {0.f, 0.f, 0.f, 0.f}, pd[4] = {0.f, 0.f, 0.f, 0.f};
#pragma unroll
    for (int t = 0; t < 8; ++t) {
        float as_ = asrc[t * 16 + m], ad_ = adst[t * 16 + m];
#pragma unroll
        for (int r = 0; r < 4; ++r) {
            float v = acc[t][r];
            ps[r] = fmaf(v, as_, ps[r]);
            pd[r] = fmaf(v, ad_, pd[r]);
            float vn = __shfl_xor(v, 1, 64);      // neighbor col
            if (!(m & 1)) {
                int grow = row0 + wave * 16 + quad * 4 + r;
                if (grow < N_NODES)
                    zb[(long)grow * 64 + t * 8 + (m >> 1)] = pack_bf2(v, vn);
            }
        }
    }
#pragma unroll
    for (int r = 0; r < 4; ++r) {
        for (int off = 1; off < 16; off <<= 1) {
            ps[r] += __shfl_xor(ps[r], off, 64);
            pd[r] += __shfl_xor(pd[r], off, 64);
        }
    }
    if (m == 0) {
#pragma unroll
        for (int r = 0; r < 4; ++r) {
            int grow = row0 + wave * 16 + quad * 4 + r;
            if (grow < N_NODES) { s_src[grow] = ps[r]; s_dst[grow] = pd[r]; }
        }
    }
}

// ---- pass 1 over edges: score + exp + histogram-with-rank, coalesced writes ----
// Round-4 lesson: the rank atomic's return must feed a COALESCED store (ranks[i]),
// never a scattered store — the atomic->scattered-store dep chain serializes.
__global__ void edge_score_hist_kernel(const float* __restrict__ efeats, const float* __restrict__ attn,
                                       const int* __restrict__ src, const int* __restrict__ dst,
                                       const float* __restrict__ s_src, const float* __restrict__ s_dst,
                                       int* __restrict__ counts, unsigned short* __restrict__ ranks,
                                       unsigned short* __restrict__ wq) {
    int i = blockIdx.x * blockDim.x + threadIdx.x;
    if (i >= N_EDGES) return;
    const float4* ef = (const float4*)(efeats + (long)i * IN_DIM_E);
    const float4* ae = (const float4*)(attn + OUT_DIM);
    float se = 0.f;
#pragma unroll
    for (int q = 0; q < IN_DIM_E / 4; ++q) {
        float4 v = ef[q];
        float4 a = ae[q];
        se += v.x * a.x + v.y * a.y + v.z * a.z + v.w * a.w;
    }
    int s = src[i], d = dst[i];
    float x = s_src[s] + se + s_dst[d];
    float ev = (x >= 0.f) ? x : 0.01f * x;
    float w = expf(ev);                   // exp(e)/sum == exp(e-m)/sum(exp(e-m))
    wq[i] = (unsigned short)bf16_rne(w);
    ranks[i] = (unsigned short)atomicAdd(&counts[d], 1);   // stable rank within dst
}

// ---------------- scan: block-local exclusive prefix + last-block finish ----------------
// Each block publishes its sum; the LAST block to finish (atomic done-counter,
// no dispatch-order assumption) exclusive-scans the 196 blocksums in place.
// Consumers add blocksums[i>>8]. Replaces the separate scan2 launch.
__launch_bounds__(256)
__global__ void scan1_kernel(const int* __restrict__ counts, int* __restrict__ offsets,
                             int* __restrict__ blocksums, int* __restrict__ done) {
    int i = blockIdx.x * 256 + threadIdx.x;
    int v = (i < N_NODES) ? counts[i] : 0;
    int lane = threadIdx.x & 63;
    int wv = threadIdx.x >> 6;
    int x = v;
    for (int off = 1; off < 64; off <<= 1) {
        int y = __shfl_up(x, off, 64);
        if (lane >= off) x += y;
    }
    __shared__ int wsum[4];
    __shared__ int slast;
    if (lane == 63) wsum[wv] = x;
    __syncthreads();
    int base = 0;
    for (int w = 0; w < wv; ++w) base += wsum[w];
    int excl = base + x - v;
    if (i <= N_NODES) offsets[i] = excl;
    if (threadIdx.x == 255) {
        blocksums[blockIdx.x] = base + x;      // publish block total
        __threadfence();                        // release
        slast = (atomicAdd(done, 1) == SCAN_BLOCKS - 1);
    }
    __syncthreads();
    if (slast) {
        __threadfence();                        // acquire: see all blocksums
        int t = threadIdx.x;
        int bv = (t < SCAN_BLOCKS) ? blocksums[t] : 0;
        int bx = bv;
        for (int off = 1; off < 64; off <<= 1) {
            int y = __shfl_up(bx, off, 64);
            if (lane >= off) bx += y;
        }
        __shared__ int wsum2[4];
        if (lane == 63) wsum2[wv] = bx;
        __syncthreads();
        int b2 = 0;
        for (int w = 0; w < wv; ++w) b2 += wsum2[w];
        if (t < SCAN_BLOCKS) blocksums[t] = b2 + bx - bv;
    }
}

// ---- pass 2 over edges: place packed (src:16 | bf16 w:16) at offsets[d]+rank ----
// Scattered store depends only on regular cached loads -> pipelines freely.
__global__ void scatter_kernel(const int* __restrict__ src, const int* __restrict__ dst,
                               const unsigned short* __restrict__ ranks,
                               const unsigned short* __restrict__ wq,
                               const int* __restrict__ offsets, const int* __restrict__ blocksums,
                               unsigned* __restrict__ pairs4) {
    int i = blockIdx.x * blockDim.x + threadIdx.x;
    if (i >= N_EDGES) return;
    int d = dst[i];
    int pos = offsets[d] + blocksums[d >> 8] + (int)ranks[i];
    pairs4[pos] = (unsigned)src[i] | ((unsigned)wq[i] << 16);
}

// ---------------- one wave per node: weighted gather of bf16 z (4-way ILP) ----------------
__launch_bounds__(256)
__global__ void aggregate_kernel(const unsigned* __restrict__ pairs4, const int* __restrict__ offsets,
                                 const int* __restrict__ blocksums,
                                 const unsigned* __restrict__ zb, float* __restrict__ h) {
    int node = blockIdx.x * 4 + (threadIdx.x >> 6);
    if (node >= N_NODES) return;
    int lane = threadIdx.x & 63;
    int beg = offsets[node] + blocksums[node >> 8];
    int end = offsets[node + 1] + blocksums[(node + 1) >> 8];
    float ax0 = 0.f, ay0 = 0.f, ax1 = 0.f, ay1 = 0.f;
    float ax2 = 0.f, ay2 = 0.f, ax3 = 0.f, ay3 = 0.f;
    float dsum = 0.f;
    for (int base = beg; base < end; base += 64) {
        int n = min(64, end - base);
        unsigned u = 0;
        if (lane < n) {
            u = pairs4[base + lane];
            dsum += __uint_as_float(u & 0xFFFF0000u);
        }
        int j = 0;
        for (; j + 3 < n; j += 4) {
            unsigned u0 = (unsigned)__shfl((int)u, j, 64);
            unsigned u1 = (unsigned)__shfl((int)u, j + 1, 64);
            unsigned u2 = (unsigned)__shfl((int)u, j + 2, 64);
            unsigned u3 = (unsigned)__shfl((int)u, j + 3, 64);
            unsigned z0 = zb[(long)(u0 & 0xFFFFu) * 64 + lane];
            unsigned z1 = zb[(long)(u1 & 0xFFFFu) * 64 + lane];
            unsigned z2 = zb[(long)(u2 & 0xFFFFu) * 64 + lane];
            unsigned z3 = zb[(long)(u3 & 0xFFFFu) * 64 + lane];
            float w0 = __uint_as_float(u0 & 0xFFFF0000u);
            float w1 = __uint_as_float(u1 & 0xFFFF0000u);
            float w2 = __uint_as_float(u2 & 0xFFFF0000u);
            float w3 = __uint_as_float(u3 & 0xFFFF0000u);
            ax0 = fmaf(w0, __uint_as_float(z0 << 16), ax0);
            ay0 = fmaf(w0, __uint_as_float(z0 & 0xFFFF0000u), ay0);
            ax1 = fmaf(w1, __uint_as_float(z1 << 16), ax1);
            ay1 = fmaf(w1, __uint_as_float(z1 & 0xFFFF0000u), ay1);
            ax2 = fmaf(w2, __uint_as_float(z2 << 16), ax2);
            ay2 = fmaf(w2, __uint_as_float(z2 & 0xFFFF0000u), ay2);
            ax3 = fmaf(w3, __uint_as_float(z3 << 16), ax3);
            ay3 = fmaf(w3, __uint_as_float(z3 & 0xFFFF0000u), ay3);
        }
        for (; j < n; ++j) {
            unsigned u0 = (unsigned)__shfl((int)u, j, 64);
            unsigned z0 = zb[(long)(u0 & 0xFFFFu) * 64 + lane];
            float w0 = __uint_as_float(u0 & 0xFFFF0000u);
            ax0 = fmaf(w0, __uint_as_float(z0 << 16), ax0);
            ay0 = fmaf(w0, __uint_as_float(z0 & 0xFFFF0000u), ay0);
        }
    }
    float accx = (ax0 + ax1) + (ax2 + ax3);
    float accy = (ay0 + ay1) + (ay2 + ay3);
    for (int off = 32; off; off >>= 1) dsum += __shfl_xor(dsum, off, 64);
    float scale = 1.f / (dsum > 0.f ? dsum : 1.f);
    ((float2*)h)[(long)node * 64 + lane] = make_float2(accx * scale, accy * scale);
}

extern "C" void kernel_launch(void* const* d_in, const int* in_sizes, int n_in,
                              void* d_out, int out_size, void* d_ws, size_t ws_size,
                              hipStream_t stream) {
    const float* nfeats = (const float*)d_in[0];
    const float* efeats = (const float*)d_in[1];
    const float* W_fc   = (const float*)d_in[2];
    const float* W_attn = (const float*)d_in[3];
    const int*   src    = (const int*)d_in[4];
    const int*   dst    = (const int*)d_in[5];
    float* h = (float*)d_out;

    char* ws = (char*)d_ws;
    unsigned* zb     = (unsigned*)ws;                              // 12.8 MB
    float* s_src     = (float*)(ws + (size_t)N_NODES * 64 * 4);
    float* s_dst     = s_src + N_NODES;
    unsigned* Wfrag  = (unsigned*)(s_dst + N_NODES);               // 8192 u32 (32 KB)
    int*   counts    = (int*)(Wfrag + 8192);
    int*   offsets   = counts + N_NODES;                           // N_NODES+1
    int*   blocksums = offsets + N_NODES + 4;                      // 196
    int*   done      = blocksums + SCAN_BLOCKS;                    // 1
    unsigned short* ranks = (unsigned short*)(done + 4);           // 800k u16
    unsigned short* wq    = ranks + N_EDGES;                       // 800k u16
    unsigned* pairs4      = (unsigned*)(wq + N_EDGES);             // 800k u32

    wfrag_kernel<<<8, 256, 0, stream>>>(W_fc, Wfrag, done);
    gemm_mfma_kernel<<<GEMM_BLOCKS, 256, 0, stream>>>(
        nfeats, Wfrag, W_attn, counts, zb, s_src, s_dst);
    edge_score_hist_kernel<<<(N_EDGES + 255) / 256, 256, 0, stream>>>(
        efeats, W_attn, src, dst, s_src, s_dst, counts, ranks, wq);
    scan1_kernel<<<SCAN_BLOCKS, 256, 0, stream>>>(counts, offsets, blocksums, done);
    scatter_kernel<<<(N_EDGES + 255) / 256, 256, 0, stream>>>(
        src, dst, ranks, wq, offsets, blocksums, pairs4);
    aggregate_kernel<<<(N_NODES + 3) / 4, 256, 0, stream>>>(pairs4, offsets, blocksums, zb, h);
}

// Round 7
// 259.113 us; speedup vs baseline: 1.0127x; 1.0127x over previous
//
#include <hip/hip_runtime.h>
#include <math.h>

#define N_NODES 50000
#define N_EDGES 800000
#define IN_DIM_N 128
#define IN_DIM_E 32
#define OUT_DIM 128
#define SCAN_BLOCKS ((N_NODES + 255) / 256)   // 196
#define GEMM_BLOCKS ((N_NODES + 63) / 64)     // 782

typedef __bf16 bf16x8 __attribute__((ext_vector_type(8)));
typedef float  f32x4  __attribute__((ext_vector_type(4)));

// bf16 pack helpers (RNE; data has no NaN/inf)
__device__ inline unsigned bf16_rne(float x) {
    unsigned u = __float_as_uint(x);
    return (u + 0x7FFFu + ((u >> 16) & 1u)) >> 16;
}
__device__ inline unsigned pack_bf2(float a, float b) {
    return bf16_rne(a) | (bf16_rne(b) << 16);
}

// ---- one-off: W_fc (128x128 fp32, W[c][k]) -> bf16 B-fragment layout ----
// Also zeroes counts (grid-stride) so no hipMemsetAsync / no zeroing elsewhere.
__global__ void wfrag_kernel(const float* __restrict__ W, unsigned* __restrict__ Wfrag,
                             int* __restrict__ counts) {
    int t = blockIdx.x * 256 + threadIdx.x;   // 0..2047
    for (int i = t; i < N_NODES; i += 2048) counts[i] = 0;
    if (t >= 2048) return;
    int lane = t & 63;
    int tile = (t >> 6) & 7;
    int ks   = t >> 9;
    int n  = tile * 16 + (lane & 15);
    int kb = ks * 32 + (lane >> 4) * 8;
    const float* srcp = W + n * 128 + kb;     // 8 consecutive k
    unsigned o[4];
#pragma unroll
    for (int j = 0; j < 4; ++j) o[j] = pack_bf2(srcp[2 * j], srcp[2 * j + 1]);
    ((uint4*)Wfrag)[t] = *(uint4*)o;
}

// ---------- MFMA GEMM: 64 rows/block, z bf16 store, fused s_src/s_dst ----------
// B-fragments read DIRECTLY from global Wfrag in the MFMA loop: 32 KB, fits L1,
// identical addresses across waves (broadcast). Proven ~10 us faster than the
// Bu-LDS staging variant (round 4 vs round 3).
__launch_bounds__(256)
__global__ void gemm_mfma_kernel(const float* __restrict__ A, const unsigned* __restrict__ Wfrag,
                                 const float* __restrict__ attn, unsigned* __restrict__ zb,
                                 float* __restrict__ s_src, float* __restrict__ s_dst) {
    __shared__ unsigned Au[64 * 68];    // A bf16, row stride 136 bf16 = 68 u32 (pad kills conflicts)
    __shared__ float asrc[128], adst[128];
    int tid = threadIdx.x;
    int row0 = blockIdx.x * 64;

    if (tid < 128) { asrc[tid] = attn[tid]; adst[tid] = attn[160 + tid]; }

    // stage A: 64 rows x 128 k, fp32 -> bf16
    for (int i = tid; i < 64 * 32; i += 256) {
        int r = i >> 5, q = i & 31;
        int gr = row0 + r;
        float4 v = make_float4(0.f, 0.f, 0.f, 0.f);
        if (gr < N_NODES) v = ((const float4*)A)[(long)gr * 32 + q];
        uint2 p = make_uint2(pack_bf2(v.x, v.y), pack_bf2(v.z, v.w));
        *((uint2*)&Au[r * 68 + q * 2]) = p;
    }
    __syncthreads();

    int lane = tid & 63;
    int wave = tid >> 6;
    int m = lane & 15, quad = lane >> 4;
    const uint4* Wg = (const uint4*)Wfrag;

    f32x4 acc[8];
#pragma unroll
    for (int t = 0; t < 8; ++t) acc[t] = (f32x4){0.f, 0.f, 0.f, 0.f};

#pragma unroll
    for (int ks = 0; ks < 4; ++ks) {
        uint4 au = *((const uint4*)&Au[(wave * 16 + m) * 68 + ks * 16 + quad * 4]);
        bf16x8 af = *(bf16x8*)&au;
#pragma unroll
        for (int t = 0; t < 8; ++t) {
            uint4 bu = Wg[(ks * 8 + t) * 64 + lane];   // L1-resident broadcast
            bf16x8 bf = *(bf16x8*)&bu;
            acc[t] = __builtin_amdgcn_mfma_f32_16x16x32_bf16(af, bf, acc[t], 0, 0, 0);
        }
    }

    // epilogue: C/D layout col=lane&15 (+tile*16), row=quad*4+reg
    float ps[4] = {0.f, 0.f, 0.f, 0.f}, pd[4] = {0.f, 0.f, 0.f, 0.f};
#pragma unroll
    for (int t = 0; t < 8; ++t) {
        float as_ = asrc[t * 16 + m], ad_ = adst[t * 16 + m];
#pragma unroll
        for (int r = 0; r < 4; ++r) {
            float v = acc[t][r];
            ps[r] = fmaf(v, as_, ps[r]);
            pd[r] = fmaf(v, ad_, pd[r]);
            float vn = __shfl_xor(v, 1, 64);      // neighbor col
            if (!(m & 1)) {
                int grow = row0 + wave * 16 + quad * 4 + r;
                if (grow < N_NODES)
                    zb[(long)grow * 64 + t * 8 + (m >> 1)] = pack_bf2(v, vn);
            }
        }
    }
#pragma unroll
    for (int r = 0; r < 4; ++r) {
        for (int off = 1; off < 16; off <<= 1) {
            ps[r] += __shfl_xor(ps[r], off, 64);
            pd[r] += __shfl_xor(pd[r], off, 64);
        }
    }
    if (m == 0) {
#pragma unroll
        for (int r = 0; r < 4; ++r) {
            int grow = row0 + wave * 16 + quad * 4 + r;
            if (grow < N_NODES) { s_src[grow] = ps[r]; s_dst[grow] = pd[r]; }
        }
    }
}

// ---- pass 1 over edges: score + exp + histogram-with-rank, coalesced writes ----
// Round-4 lesson: the rank atomic's return must feed a COALESCED store,
// never a scattered store — the atomic->scattered-store dep chain serializes.
// rank and wq packed into ONE u32 (rank<<16 | wq): one store here, one load in scatter.
__global__ void edge_score_hist_kernel(const float* __restrict__ efeats, const float* __restrict__ attn,
                                       const int* __restrict__ src, const int* __restrict__ dst,
                                       const float* __restrict__ s_src, const float* __restrict__ s_dst,
                                       int* __restrict__ counts, unsigned* __restrict__ rw) {
    int i = blockIdx.x * blockDim.x + threadIdx.x;
    if (i >= N_EDGES) return;
    const float4* ef = (const float4*)(efeats + (long)i * IN_DIM_E);
    const float4* ae = (const float4*)(attn + OUT_DIM);
    float se = 0.f;
#pragma unroll
    for (int q = 0; q < IN_DIM_E / 4; ++q) {
        float4 v = ef[q];
        float4 a = ae[q];
        se += v.x * a.x + v.y * a.y + v.z * a.z + v.w * a.w;
    }
    int s = src[i], d = dst[i];
    float x = s_src[s] + se + s_dst[d];
    float ev = (x >= 0.f) ? x : 0.01f * x;
    float w = expf(ev);                   // exp(e)/sum == exp(e-m)/sum(exp(e-m))
    unsigned rank = (unsigned)atomicAdd(&counts[d], 1);   // stable rank within dst (max deg ~45)
    rw[i] = (rank << 16) | bf16_rne(w);
}

// ---------------- scan pass 1: block-local exclusive prefix + blocksums ----------------
// Consumers add blocksums[i>>8] after scan2 finalizes it (no scan3 pass).
__launch_bounds__(256)
__global__ void scan1_kernel(const int* __restrict__ counts, int* __restrict__ offsets,
                             int* __restrict__ blocksums) {
    int i = blockIdx.x * 256 + threadIdx.x;
    int v = (i < N_NODES) ? counts[i] : 0;
    int lane = threadIdx.x & 63;
    int wv = threadIdx.x >> 6;
    int x = v;
    for (int off = 1; off < 64; off <<= 1) {
        int y = __shfl_up(x, off, 64);
        if (lane >= off) x += y;
    }
    __shared__ int wsum[4];
    if (lane == 63) wsum[wv] = x;
    __syncthreads();
    int base = 0;
    for (int w = 0; w < wv; ++w) base += wsum[w];
    int excl = base + x - v;
    if (i <= N_NODES) offsets[i] = excl;
    if (threadIdx.x == 255) blocksums[blockIdx.x] = base + x;
}

// ---------------- scan pass 2: exclusive scan of 196 block sums ----------------
__launch_bounds__(256)
__global__ void scan2_kernel(int* __restrict__ blocksums) {
    int t = threadIdx.x;
    int v = (t < SCAN_BLOCKS) ? blocksums[t] : 0;
    int lane = t & 63;
    int wv = t >> 6;
    int x = v;
    for (int off = 1; off < 64; off <<= 1) {
        int y = __shfl_up(x, off, 64);
        if (lane >= off) x += y;
    }
    __shared__ int wsum[4];
    if (lane == 63) wsum[wv] = x;
    __syncthreads();
    int base = 0;
    for (int w = 0; w < wv; ++w) base += wsum[w];
    if (t < SCAN_BLOCKS) blocksums[t] = base + x - v;
}

// ---- pass 2 over edges: place packed (src:16 | bf16 w:16) at offsets[d]+rank ----
// Scattered store depends only on regular cached loads -> pipelines freely.
__global__ void scatter_kernel(const int* __restrict__ src, const int* __restrict__ dst,
                               const unsigned* __restrict__ rw,
                               const int* __restrict__ offsets, const int* __restrict__ blocksums,
                               unsigned* __restrict__ pairs4) {
    int i = blockIdx.x * blockDim.x + threadIdx.x;
    if (i >= N_EDGES) return;
    int d = dst[i];
    unsigned u = rw[i];
    int pos = offsets[d] + blocksums[d >> 8] + (int)(u >> 16);
    pairs4[pos] = (unsigned)src[i] | (u << 16);
}

// ---------------- one wave per node: weighted gather of bf16 z (4-way ILP) ----------------
__launch_bounds__(256)
__global__ void aggregate_kernel(const unsigned* __restrict__ pairs4, const int* __restrict__ offsets,
                                 const int* __restrict__ blocksums,
                                 const unsigned* __restrict__ zb, float* __restrict__ h) {
    int node = blockIdx.x * 4 + (threadIdx.x >> 6);
    if (node >= N_NODES) return;
    int lane = threadIdx.x & 63;
    int beg = offsets[node] + blocksums[node >> 8];
    int end = offsets[node + 1] + blocksums[(node + 1) >> 8];
    float ax0 = 0.f, ay0 = 0.f, ax1 = 0.f, ay1 = 0.f;
    float ax2 = 0.f, ay2 = 0.f, ax3 = 0.f, ay3 = 0.f;
    float dsum = 0.f;
    for (int base = beg; base < end; base += 64) {
        int n = min(64, end - base);
        unsigned u = 0;
        if (lane < n) {
            u = pairs4[base + lane];
            dsum += __uint_as_float(u & 0xFFFF0000u);
        }
        int j = 0;
        for (; j + 3 < n; j += 4) {
            unsigned u0 = (unsigned)__shfl((int)u, j, 64);
            unsigned u1 = (unsigned)__shfl((int)u, j + 1, 64);
            unsigned u2 = (unsigned)__shfl((int)u, j + 2, 64);
            unsigned u3 = (unsigned)__shfl((int)u, j + 3, 64);
            unsigned z0 = zb[(long)(u0 & 0xFFFFu) * 64 + lane];
            unsigned z1 = zb[(long)(u1 & 0xFFFFu) * 64 + lane];
            unsigned z2 = zb[(long)(u2 & 0xFFFFu) * 64 + lane];
            unsigned z3 = zb[(long)(u3 & 0xFFFFu) * 64 + lane];
            float w0 = __uint_as_float(u0 & 0xFFFF0000u);
            float w1 = __uint_as_float(u1 & 0xFFFF0000u);
            float w2 = __uint_as_float(u2 & 0xFFFF0000u);
            float w3 = __uint_as_float(u3 & 0xFFFF0000u);
            ax0 = fmaf(w0, __uint_as_float(z0 << 16), ax0);
            ay0 = fmaf(w0, __uint_as_float(z0 & 0xFFFF0000u), ay0);
            ax1 = fmaf(w1, __uint_as_float(z1 << 16), ax1);
            ay1 = fmaf(w1, __uint_as_float(z1 & 0xFFFF0000u), ay1);
            ax2 = fmaf(w2, __uint_as_float(z2 << 16), ax2);
            ay2 = fmaf(w2, __uint_as_float(z2 & 0xFFFF0000u), ay2);
            ax3 = fmaf(w3, __uint_as_float(z3 << 16), ax3);
            ay3 = fmaf(w3, __uint_as_float(z3 & 0xFFFF0000u), ay3);
        }
        for (; j < n; ++j) {
            unsigned u0 = (unsigned)__shfl((int)u, j, 64);
            unsigned z0 = zb[(long)(u0 & 0xFFFFu) * 64 + lane];
            float w0 = __uint_as_float(u0 & 0xFFFF0000u);
            ax0 = fmaf(w0, __uint_as_float(z0 << 16), ax0);
            ay0 = fmaf(w0, __uint_as_float(z0 & 0xFFFF0000u), ay0);
        }
    }
    float accx = (ax0 + ax1) + (ax2 + ax3);
    float accy = (ay0 + ay1) + (ay2 + ay3);
    for (int off = 32; off; off >>= 1) dsum += __shfl_xor(dsum, off, 64);
    float scale = 1.f / (dsum > 0.f ? dsum : 1.f);
    ((float2*)h)[(long)node * 64 + lane] = make_float2(accx * scale, accy * scale);
}

extern "C" void kernel_launch(void* const* d_in, const int* in_sizes, int n_in,
                              void* d_out, int out_size, void* d_ws, size_t ws_size,
                              hipStream_t stream) {
    const float* nfeats = (const float*)d_in[0];
    const float* efeats = (const float*)d_in[1];
    const float* W_fc   = (const float*)d_in[2];
    const float* W_attn = (const float*)d_in[3];
    const int*   src    = (const int*)d_in[4];
    const int*   dst    = (const int*)d_in[5];
    float* h = (float*)d_out;

    char* ws = (char*)d_ws;
    unsigned* zb     = (unsigned*)ws;                              // 12.8 MB
    float* s_src     = (float*)(ws + (size_t)N_NODES * 64 * 4);
    float* s_dst     = s_src + N_NODES;
    unsigned* Wfrag  = (unsigned*)(s_dst + N_NODES);               // 8192 u32 (32 KB)
    int*   counts    = (int*)(Wfrag + 8192);
    int*   offsets   = counts + N_NODES;                           // N_NODES+1
    int*   blocksums = offsets + N_NODES + 4;                      // 196
    unsigned* rw     = (unsigned*)(blocksums + SCAN_BLOCKS + 4);   // 800k u32 (rank<<16|wq)
    unsigned* pairs4 = rw + N_EDGES;                               // 800k u32

    wfrag_kernel<<<8, 256, 0, stream>>>(W_fc, Wfrag, counts);
    gemm_mfma_kernel<<<GEMM_BLOCKS, 256, 0, stream>>>(
        nfeats, Wfrag, W_attn, zb, s_src, s_dst);
    edge_score_hist_kernel<<<(N_EDGES + 255) / 256, 256, 0, stream>>>(
        efeats, W_attn, src, dst, s_src, s_dst, counts, rw);
    scan1_kernel<<<SCAN_BLOCKS, 256, 0, stream>>>(counts, offsets, blocksums);
    scan2_kernel<<<1, 256, 0, stream>>>(blocksums);
    scatter_kernel<<<(N_EDGES + 255) / 256, 256, 0, stream>>>(
        src, dst, rw, offsets, blocksums, pairs4);
    aggregate_kernel<<<(N_NODES + 3) / 4, 256, 0, stream>>>(pairs4, offsets, blocksums, zb, h);
}